// Round 5
// baseline (11404.933 us; speedup 1.0000x reference)
//
#include <hip/hip_runtime.h>

typedef __attribute__((ext_vector_type(8))) short short8;
typedef __attribute__((ext_vector_type(4))) float f32x4;
typedef __attribute__((ext_vector_type(4))) int int4v;
typedef __attribute__((ext_vector_type(4))) unsigned short u16x4;
typedef unsigned short u16;

#define T_LEN 256
#define BATCH 64
#define HID   1024
#define GDIM  4128
#define BH    65536
#define NWG   128

__device__ __forceinline__ u16 f2bf(float f){
  unsigned u = __builtin_bit_cast(unsigned, f);
  return (u16)((u + 0x7fffu + ((u >> 16) & 1u)) >> 16);
}

// ---- prologue kernels -------------------------------------------------------

__global__ __launch_bounds__(1024) void repackW(const float* __restrict__ Wih,
                                                const float* __restrict__ Whh,
                                                u16* __restrict__ Wt)
{
  __shared__ float tile[32][33];
  int k = blockIdx.x * 32 + threadIdx.y;
  int c = blockIdx.y * 32 + threadIdx.x;
  float v = (k < 1024) ? Wih[(size_t)k * GDIM + c]
                       : Whh[(size_t)(k - 1024) * GDIM + c];
  tile[threadIdx.y][threadIdx.x] = v;
  __syncthreads();
  int c2 = blockIdx.y * 32 + threadIdx.y;
  int k2 = blockIdx.x * 32 + threadIdx.x;
  Wt[(size_t)c2 * 2048 + k2] = f2bf(tile[threadIdx.x][threadIdx.y]);
}

__global__ __launch_bounds__(256) void gatherX(const int* __restrict__ tokens,
                                               const float* __restrict__ emb,
                                               u16* __restrict__ x,
                                               float* __restrict__ maskout)
{
  int idx = blockIdx.x;
  int tok = tokens[idx];
  const f32x4* src = (const f32x4*)&emb[(size_t)tok * HID];
  f32x4 v = src[threadIdx.x];
  u16x4 o;
  #pragma unroll
  for (int j = 0; j < 4; ++j) o[j] = f2bf(v[j]);
  *(u16x4*)&x[(size_t)idx * HID + threadIdx.x * 4] = o;
  if (threadIdx.x == 0) maskout[idx] = (tok != 0) ? 1.0f : 0.0f;
}

__global__ __launch_bounds__(256) void biasK(const float* __restrict__ bih0, const float* __restrict__ bhh0,
                                             const float* __restrict__ bih1, const float* __restrict__ bhh1,
                                             float* __restrict__ bias0, float* __restrict__ bias1)
{
  int i = blockIdx.x * 256 + threadIdx.x;
  if (i < GDIM){ bias0[i] = bih0[i] + bhh0[i]; bias1[i] = bih1[i] + bhh1[i]; }
}

__global__ __launch_bounds__(256) void zeroK(int4v* __restrict__ p)
{
  int4v z = {0,0,0,0};
  p[blockIdx.x * 256 + threadIdx.x] = z;
}

// ---- barrier: relaxed atomics, 8 sharded counter lines ----------------------
__device__ __forceinline__ void drain_sync(){
  asm volatile("s_waitcnt vmcnt(0)" ::: "memory");
  __syncthreads();
}
__device__ __forceinline__ void bar_add(unsigned* set, int wg){
  if (threadIdx.x == 0)
    __hip_atomic_fetch_add(&set[(wg & 7) * 32], 1u, __ATOMIC_RELAXED, __HIP_MEMORY_SCOPE_AGENT);
}
__device__ __forceinline__ void bar_spin(unsigned* set, unsigned target){
  if (threadIdx.x == 0){
    for (;;){
      unsigned sm = 0;
      #pragma unroll
      for (int i = 0; i < 8; ++i)
        sm += __hip_atomic_load(&set[i * 32], __ATOMIC_RELAXED, __HIP_MEMORY_SCOPE_AGENT);
      if (sm >= target) break;
      __builtin_amdgcn_s_sleep(8);
    }
  }
  __syncthreads();
}

// ---- fused persistent kernel: ONE barrier per epoch -------------------------
// 128 WGs x 512 thr, 1 WG/CU. WG w: lay = w>>6, owns h-elems E0..E0+15
// (E0 = (w&63)*16). Per epoch s: layer-0 does t=s, layer-1 does t=s-2.
// Critical: h_prev @ [LDS rest-weights (64 cols, K=1024) + global sm cols
// (32, K=1024)] + slack-acc -> gates (regs) -> LDS transpose -> gating ->
// volatile h write -> drain -> bar_add. Slack: next epoch's non-recurrent
// product (x@W_ih0 / h1@W_ih1, all 96 cols, global weights) -> bar_spin.
__global__ __launch_bounds__(512, 1) void persist(
    const u16* __restrict__ Wt0, const u16* __restrict__ Wt1,
    const float* __restrict__ bias0, const float* __restrict__ bias1,
    const u16* __restrict__ x, u16* __restrict__ hA, u16* __restrict__ hB,
    const u16* __restrict__ zerob,
    float* __restrict__ out, unsigned* __restrict__ bar)
{
  __shared__ __align__(16) u16 Ws[65536];       // 128KB rest weights
  __shared__ __align__(16) float smT[32 * 68 + 4];   // sm logits transpose
  __shared__ __align__(16) float restT[64 * 68 + 4]; // rest gates transpose

  const int wg = blockIdx.x, tid = threadIdx.x;
  const int wave = tid >> 6, lane = tid & 63;
  const int lo = lane & 15, hi = lane >> 4, khi = hi * 8;
  const int mt = wave >> 1, nw = wave & 1;       // 4 M-tiles x 2 halves
  const int row = mt * 16 + lo;
  const int lay = wg >> 6;
  const int E0 = (wg & 63) * 16;
  const u16* Wt = lay ? Wt1 : Wt0;
  const float* bias = lay ? bias1 : bias0;

  // one-time staging: 64 rest cols x K=1024 (recurrent k-half), XOR-swizzled
  for (int i = tid; i < 64 * 128; i += 512){
    int c = i >> 7, ck = (i & 127) << 3;
    int gcol = 32 + (c >> 4) * 1024 + E0 + (c & 15);
    *(int4v*)&Ws[c * 1024 + (ck ^ ((c & 7) << 3))] =
        *(const int4v*)&Wt[(size_t)gcol * 2048 + 1024 + ck];
  }

  // wave's 3 N-tiles: nw=0 -> {sm1, sm2, og}; nw=1 -> {cell, in, fg}
  int tb0, tb1, tb2;                 // global col base of each tile
  if (nw == 0){ tb0 = 0;               tb1 = 16;              tb2 = 32 + E0; }
  else        { tb0 = 32 + 1024 + E0;  tb1 = 32 + 2048 + E0;  tb2 = 32 + 3072 + E0; }
  const float bv0 = bias[tb0 + lo], bv1 = bias[tb1 + lo], bv2 = bias[tb2 + lo];
  const u16* gB0 = Wt + (size_t)(tb0 + lo) * 2048;
  const u16* gB1 = Wt + (size_t)(tb1 + lo) * 2048;
  const u16* gB2 = Wt + (size_t)(tb2 + lo) * 2048;

  f32x4 xn0, xn1, xn2;               // slack accumulators (bias + x-part)

  auto ldsB = [&](int c, int k)->short8 {
    return *(const short8*)&Ws[c * 1024 + (k ^ ((c & 7) << 3))];
  };

  auto slack_mm = [&](const u16* Asrc){
    f32x4 s0 = {bv0,bv0,bv0,bv0}, s1 = {bv1,bv1,bv1,bv1}, s2 = {bv2,bv2,bv2,bv2};
    const u16* pA = Asrc + row * HID;
    #pragma unroll 1
    for (int blk = 0; blk < 4; ++blk){
      short8 A[8], B0[8], B1[8], B2[8];
      #pragma unroll
      for (int i = 0; i < 8; ++i){
        int k = (blk * 8 + i) * 32 + khi;
        A[i]  = *(const short8*)(pA + k);
        B0[i] = *(const short8*)(gB0 + k);
        B1[i] = *(const short8*)(gB1 + k);
        B2[i] = *(const short8*)(gB2 + k);
      }
      #pragma unroll
      for (int i = 0; i < 8; ++i){
        s0 = __builtin_amdgcn_mfma_f32_16x16x32_bf16(A[i], B0[i], s0, 0,0,0);
        s1 = __builtin_amdgcn_mfma_f32_16x16x32_bf16(A[i], B1[i], s1, 0,0,0);
        s2 = __builtin_amdgcn_mfma_f32_16x16x32_bf16(A[i], B2[i], s2, 0,0,0);
      }
    }
    xn0 = s0; xn1 = s1; xn2 = s2;
  };

  f32x4 creg = {0.f, 0.f, 0.f, 0.f};
  if (lay == 0) slack_mm(x);         // xn for t=0

  for (int s = 0; s <= 257; ++s){
    const int t = lay ? (s - 2) : s;
    const bool act = (t >= 0) && (t < T_LEN);
    if (act){
      // ---- critical matmul: a = xn + h_prev @ W_rec ----
      const u16* Asrc;
      if (lay == 0) Asrc = (s == 0) ? zerob : (hA + (size_t)(s - 1) * BH);
      else          Asrc = (t == 0) ? zerob : (hB + (size_t)(t - 1) * BH);
      f32x4 a0 = xn0, a1 = xn1, a2 = xn2;
      const u16* pA = Asrc + row * HID;
      if (nw == 0){
        #pragma unroll 1
        for (int blk = 0; blk < 4; ++blk){
          short8 A[8], B0[8], B1[8];
          #pragma unroll
          for (int i = 0; i < 8; ++i){
            int k = (blk * 8 + i) * 32 + khi;
            A[i]  = *(const short8*)(pA + k);
            B0[i] = *(const short8*)(gB0 + 1024 + k);
            B1[i] = *(const short8*)(gB1 + 1024 + k);
          }
          #pragma unroll
          for (int i = 0; i < 8; ++i){
            int k = (blk * 8 + i) * 32 + khi;
            a0 = __builtin_amdgcn_mfma_f32_16x16x32_bf16(A[i], B0[i], a0, 0,0,0);
            a1 = __builtin_amdgcn_mfma_f32_16x16x32_bf16(A[i], B1[i], a1, 0,0,0);
            a2 = __builtin_amdgcn_mfma_f32_16x16x32_bf16(A[i], ldsB(lo, k), a2, 0,0,0);
          }
        }
      } else {
        #pragma unroll 1
        for (int blk = 0; blk < 4; ++blk){
          short8 A[8];
          #pragma unroll
          for (int i = 0; i < 8; ++i)
            A[i] = *(const short8*)(pA + (blk * 8 + i) * 32 + khi);
          #pragma unroll
          for (int i = 0; i < 8; ++i){
            int k = (blk * 8 + i) * 32 + khi;
            a0 = __builtin_amdgcn_mfma_f32_16x16x32_bf16(A[i], ldsB(16 + lo, k), a0, 0,0,0);
            a1 = __builtin_amdgcn_mfma_f32_16x16x32_bf16(A[i], ldsB(32 + lo, k), a1, 0,0,0);
            a2 = __builtin_amdgcn_mfma_f32_16x16x32_bf16(A[i], ldsB(48 + lo, k), a2, 0,0,0);
          }
        }
      }
      // ---- transpose via LDS: col-major acc -> per-row ----
      const int r0 = mt * 16 + hi * 4;
      if (nw == 0){
        *(f32x4*)&smT[(lo)      * 68 + r0] = a0;
        *(f32x4*)&smT[(16 + lo) * 68 + r0] = a1;
        *(f32x4*)&restT[(lo)    * 68 + r0] = a2;
      } else {
        *(f32x4*)&restT[(16 + lo) * 68 + r0] = a0;
        *(f32x4*)&restT[(32 + lo) * 68 + r0] = a1;
        *(f32x4*)&restT[(48 + lo) * 68 + r0] = a2;
      }
      __syncthreads();
      // ---- gating: thread -> (row r, elems e0..e0+3) ----
      if (tid < 256){
        const int r = tid >> 2, e0 = (tid & 3) * 4;
        const int n = E0 >> 6;
        float m1 = -1e30f, m2 = -1e30f;
        float l1[16], l2[16];
        #pragma unroll
        for (int i = 0; i < 16; ++i){
          l1[i] = smT[i * 68 + r]; l2[i] = smT[(16 + i) * 68 + r];
          m1 = fmaxf(m1, l1[i]);   m2 = fmaxf(m2, l2[i]);
        }
        float s1 = 0.f, s2 = 0.f, cu1 = 0.f, cu2 = 0.f;
        #pragma unroll
        for (int i = 0; i < 16; ++i){
          float e1 = __expf(l1[i] - m1), e2 = __expf(l2[i] - m2);
          s1 += e1; s2 += e2;
          if (i <= n){ cu1 += e1; cu2 += e2; }
        }
        const float cin = 1.f - cu1 / s1;
        const float cf  = cu2 / s2;
        const float ov  = cf * cin;
        if (t == 0) creg = f32x4{0.f, 0.f, 0.f, 0.f};
        f32x4 hy;
        #pragma unroll
        for (int j = 0; j < 4; ++j){
          float og = restT[(e0 + j) * 68 + r];
          float ce = restT[(16 + e0 + j) * 68 + r];
          float ig = restT[(32 + e0 + j) * 68 + r];
          float fg = restT[(48 + e0 + j) * 68 + r];
          float ogv = 1.f / (1.f + __expf(-og));
          float inv = 1.f / (1.f + __expf(-ig));
          float fgv = 1.f / (1.f + __expf(-fg));
          float cev = tanhf(ce);
          float fga = fgv * ov + (cf - ov);
          float iga = inv * ov + (cin - ov);
          float cy  = fga * creg[j] + iga * cev;
          creg[j] = cy;
          hy[j] = ogv * tanhf(cy);
        }
        u16x4 hb;
        #pragma unroll
        for (int j = 0; j < 4; ++j) hb[j] = f2bf(hy[j]);
        if (lay == 0){
          *(volatile u16x4*)&hA[(size_t)t * BH + r * HID + E0 + e0] = hb;
        } else {
          *(f32x4*)&out[((size_t)t * BATCH + r) * HID + E0 + e0] = hy;
          *(volatile u16x4*)&hB[(size_t)t * BH + r * HID + E0 + e0] = hb;
        }
      }
    }
    drain_sync();
    bar_add(bar, wg);
    // ---- slack: next epoch's non-recurrent product ----
    if (lay == 0){
      if (s + 1 <= T_LEN - 1) slack_mm(x + (size_t)(s + 1) * BH);
    } else {
      if (s >= 1 && s <= T_LEN) slack_mm(hA + (size_t)(s - 1) * BH);
    }
    bar_spin(bar, (unsigned)NWG * (unsigned)(s + 1));
  }
}

// ---- launch -----------------------------------------------------------------

extern "C" void kernel_launch(void* const* d_in, const int* in_sizes, int n_in,
                              void* d_out, int out_size, void* d_ws, size_t ws_size,
                              hipStream_t stream)
{
  (void)in_sizes; (void)n_in; (void)out_size; (void)ws_size;
  const int*   tokens = (const int*)d_in[0];
  const float* emb    = (const float*)d_in[1];
  const float* Wih0   = (const float*)d_in[2];
  const float* bih0   = (const float*)d_in[3];
  const float* Whh0   = (const float*)d_in[4];
  const float* bhh0   = (const float*)d_in[5];
  const float* Wih1   = (const float*)d_in[6];
  const float* bih1   = (const float*)d_in[7];
  const float* Whh1   = (const float*)d_in[8];
  const float* bhh1   = (const float*)d_in[9];
  float* out = (float*)d_out;

  char* ws = (char*)d_ws;
  u16*   Wt0    = (u16*)(ws);                     // 16,908,288
  u16*   Wt1    = (u16*)(ws + 16908288);          // 16,908,288
  u16*   x      = (u16*)(ws + 33816576);          // 33,554,432
  u16*   hA     = (u16*)(ws + 67371008);          // 33,554,432 (h1 full history)
  u16*   hB     = (u16*)(ws + 100925440);         // 33,554,432 (h2 full history)
  float* bias0  = (float*)(ws + 134479872);       // 16,512
  float* bias1  = (float*)(ws + 134496384);       // 16,512
  u16*   zerob  = (u16*)(ws + 134512896);         // 131,072 (zeroed)
  unsigned* bar = (unsigned*)(ws + 134643968);    // 1,024
  // total 134,644,992 bytes

  repackW<<<dim3(64,129), dim3(32,32), 0, stream>>>(Wih0, Whh0, Wt0);
  repackW<<<dim3(64,129), dim3(32,32), 0, stream>>>(Wih1, Whh1, Wt1);
  gatherX<<<16384, 256, 0, stream>>>(tokens, emb, x, out + 16777216);
  biasK<<<17, 256, 0, stream>>>(bih0, bhh0, bih1, bhh1, bias0, bias1);
  zeroK<<<32, 256, 0, stream>>>((int4v*)zerob);
  hipMemsetAsync(bar, 0, 1024, stream);

  persist<<<NWG, 512, 0, stream>>>(Wt0, Wt1, bias0, bias1, x, hA, hB, zerob,
                                   out, bar);
}

// Round 6
// 8190.454 us; speedup vs baseline: 1.3925x; 1.3925x over previous
//
#include <hip/hip_runtime.h>

typedef __attribute__((ext_vector_type(8))) short short8;
typedef __attribute__((ext_vector_type(4))) float f32x4;
typedef __attribute__((ext_vector_type(4))) int int4v;
typedef __attribute__((ext_vector_type(4))) unsigned short u16x4;
typedef unsigned short u16;

#define T_LEN 256
#define BATCH 64
#define HID   1024
#define GDIM  4128
#define BH    65536
#define NWG   256

__device__ __forceinline__ u16 f2bf(float f){
  unsigned u = __builtin_bit_cast(unsigned, f);
  return (u16)((u + 0x7fffu + ((u >> 16) & 1u)) >> 16);
}

// ---- prologue kernels -------------------------------------------------------

__global__ __launch_bounds__(1024) void repackW(const float* __restrict__ Wih,
                                                const float* __restrict__ Whh,
                                                u16* __restrict__ Wt)
{
  __shared__ float tile[32][33];
  int k = blockIdx.x * 32 + threadIdx.y;
  int c = blockIdx.y * 32 + threadIdx.x;
  float v = (k < 1024) ? Wih[(size_t)k * GDIM + c]
                       : Whh[(size_t)(k - 1024) * GDIM + c];
  tile[threadIdx.y][threadIdx.x] = v;
  __syncthreads();
  int c2 = blockIdx.y * 32 + threadIdx.y;
  int k2 = blockIdx.x * 32 + threadIdx.x;
  Wt[(size_t)c2 * 2048 + k2] = f2bf(tile[threadIdx.x][threadIdx.y]);
}

__global__ __launch_bounds__(256) void gatherX(const int* __restrict__ tokens,
                                               const float* __restrict__ emb,
                                               u16* __restrict__ x,
                                               float* __restrict__ maskout)
{
  int idx = blockIdx.x;
  int tok = tokens[idx];
  const f32x4* src = (const f32x4*)&emb[(size_t)tok * HID];
  f32x4 v = src[threadIdx.x];
  u16x4 o;
  #pragma unroll
  for (int j = 0; j < 4; ++j) o[j] = f2bf(v[j]);
  *(u16x4*)&x[(size_t)idx * HID + threadIdx.x * 4] = o;
  if (threadIdx.x == 0) maskout[idx] = (tok != 0) ? 1.0f : 0.0f;
}

__global__ __launch_bounds__(256) void biasK(const float* __restrict__ bih0, const float* __restrict__ bhh0,
                                             const float* __restrict__ bih1, const float* __restrict__ bhh1,
                                             float* __restrict__ bias0, float* __restrict__ bias1)
{
  int i = blockIdx.x * 256 + threadIdx.x;
  if (i < GDIM){ bias0[i] = bih0[i] + bhh0[i]; bias1[i] = bih1[i] + bhh1[i]; }
}

// ---- fused persistent kernel ------------------------------------------------
// 256 WGs x 512 thr, 1 WG/CU (148KB LDS). WG w: lay = w>>7, owns h-elems
// E0..E0+7 (E0 = (w&127)*8). Rest-gate weights (32 cols x K=2048) LDS-resident;
// sm cols (0..31, shared) from global (L2-resident, = first 64KB-pairs of Wt).
// Epoch s: L0 computes t=s, L1 computes t=s-2. Critical = h_prev @ hh-half
// (+xn init); slack (after arrival, before wait) = next input @ ih-half.
// Gates never leave the WG (LDS transpose -> gating). ONE barrier per epoch:
// slot-store arrival, master scans + sets flag, others poll flag.
__global__ __launch_bounds__(512, 1) void persist(
    const u16* __restrict__ Wt0, const u16* __restrict__ Wt1,
    const float* __restrict__ bias0, const float* __restrict__ bias1,
    const u16* __restrict__ x, u16* __restrict__ hA, u16* __restrict__ hB,
    float* __restrict__ out, unsigned* __restrict__ slots,
    unsigned* __restrict__ flag)
{
  __shared__ __align__(16) u16 Ws[32 * 2048];      // 128KB rest weights (ih+hh)
  __shared__ __align__(16) float smT[32 * 68];     // sm logits, [col][row]
  __shared__ __align__(16) float restT[32 * 68];   // rest gates, [col][row]

  const int wg = blockIdx.x, tid = threadIdx.x;
  const int lane = tid & 63, wave = tid >> 6;
  const int lo = lane & 15, hi = lane >> 4, khi = hi * 8;
  const int mt = wave >> 1, nw = wave & 1;         // 4 M-tiles x 2 tile-groups
  const int row = mt * 16 + lo;
  const int lay = wg >> 7;
  const int E0 = (wg & 127) * 8;
  const u16* Wt = lay ? Wt1 : Wt0;
  const float* bias = lay ? bias1 : bias0;

  auto gcol = [&](int c){ return 32 + (c >> 3) * 1024 + E0 + (c & 7); };

  // one-time staging: 32 rest cols x K=2048, XOR-swizzled (16B-preserving)
  for (int i = tid; i < 32 * 256; i += 512){
    int c = i >> 8, ck = (i & 255) << 3;
    *(int4v*)&Ws[c * 2048 + (ck ^ ((c & 7) << 3))] =
        *(const int4v*)&Wt[(size_t)gcol(c) * 2048 + ck];
  }

  // per-wave tiles: nw=0 -> sm cols {lo, 16+lo} (global B); nw=1 -> rest
  // local cols {lo, 16+lo} (LDS B). Bias folded into slack init.
  float bv0, bv1;
  const u16 *gB0 = nullptr, *gB1 = nullptr;
  if (nw == 0){
    bv0 = bias[lo]; bv1 = bias[16 + lo];
    gB0 = Wt + (size_t)lo * 2048;
    gB1 = Wt + (size_t)(16 + lo) * 2048;
  } else {
    bv0 = bias[gcol(lo)]; bv1 = bias[gcol(16 + lo)];
  }
  __syncthreads();

  auto ldsB = [&](int c, int k)->short8 {
    return *(const short8*)&Ws[c * 2048 + (k ^ ((c & 7) << 3))];
  };

  f32x4 xn0, xn1;                    // slack accumulators (bias + ih-part)
  auto slack_mm = [&](const u16* Asrc){
    f32x4 s0 = {bv0,bv0,bv0,bv0}, s1 = {bv1,bv1,bv1,bv1};
    const u16* pA = Asrc + (size_t)row * HID;
    if (nw == 0){
      #pragma unroll 1
      for (int blk = 0; blk < 4; ++blk){
        short8 A[8], B0[8], B1[8];
        #pragma unroll
        for (int i = 0; i < 8; ++i){
          int k = (blk * 8 + i) * 32 + khi;
          A[i]  = *(const short8*)(pA + k);
          B0[i] = *(const short8*)(gB0 + k);
          B1[i] = *(const short8*)(gB1 + k);
        }
        #pragma unroll
        for (int i = 0; i < 8; ++i){
          s0 = __builtin_amdgcn_mfma_f32_16x16x32_bf16(A[i], B0[i], s0, 0,0,0);
          s1 = __builtin_amdgcn_mfma_f32_16x16x32_bf16(A[i], B1[i], s1, 0,0,0);
        }
      }
    } else {
      #pragma unroll 1
      for (int blk = 0; blk < 4; ++blk){
        short8 A[8];
        #pragma unroll
        for (int i = 0; i < 8; ++i)
          A[i] = *(const short8*)(pA + (blk * 8 + i) * 32 + khi);
        #pragma unroll
        for (int i = 0; i < 8; ++i){
          int k = (blk * 8 + i) * 32 + khi;
          s0 = __builtin_amdgcn_mfma_f32_16x16x32_bf16(A[i], ldsB(lo, k), s0, 0,0,0);
          s1 = __builtin_amdgcn_mfma_f32_16x16x32_bf16(A[i], ldsB(16 + lo, k), s1, 0,0,0);
        }
      }
    }
    xn0 = s0; xn1 = s1;
  };

  float creg = 0.f;                  // c-state: one scalar per thread
  if (lay == 0) slack_mm(x);         // xn for t=0

  for (int s = 0; s <= 257; ++s){
    const int t = lay ? (s - 2) : s;
    const bool act = (t >= 0) && (t < T_LEN);
    if (act){
      f32x4 a0 = xn0, a1 = xn1;
      if (t > 0){
        const u16* Asrc = lay ? (hB + (size_t)(t - 1) * BH)
                              : (hA + (size_t)(s - 1) * BH);
        const u16* pA = Asrc + (size_t)row * HID;
        if (nw == 0){
          #pragma unroll 1
          for (int blk = 0; blk < 4; ++blk){
            short8 A[8], B0[8], B1[8];
            #pragma unroll
            for (int i = 0; i < 8; ++i){
              int k = (blk * 8 + i) * 32 + khi;
              A[i]  = *(const short8*)(pA + k);
              B0[i] = *(const short8*)(gB0 + 1024 + k);
              B1[i] = *(const short8*)(gB1 + 1024 + k);
            }
            #pragma unroll
            for (int i = 0; i < 8; ++i){
              a0 = __builtin_amdgcn_mfma_f32_16x16x32_bf16(A[i], B0[i], a0, 0,0,0);
              a1 = __builtin_amdgcn_mfma_f32_16x16x32_bf16(A[i], B1[i], a1, 0,0,0);
            }
          }
        } else {
          #pragma unroll 1
          for (int blk = 0; blk < 4; ++blk){
            short8 A[8];
            #pragma unroll
            for (int i = 0; i < 8; ++i)
              A[i] = *(const short8*)(pA + (blk * 8 + i) * 32 + khi);
            #pragma unroll
            for (int i = 0; i < 8; ++i){
              int k = 1024 + (blk * 8 + i) * 32 + khi;
              a0 = __builtin_amdgcn_mfma_f32_16x16x32_bf16(A[i], ldsB(lo, k), a0, 0,0,0);
              a1 = __builtin_amdgcn_mfma_f32_16x16x32_bf16(A[i], ldsB(16 + lo, k), a1, 0,0,0);
            }
          }
        }
      }
      // transpose acc -> per-row layout (C/D: col=lane&15, row=(lane>>4)*4+j)
      const int r0 = mt * 16 + hi * 4;
      if (nw == 0){
        *(f32x4*)&smT[lo * 68 + r0] = a0;
        *(f32x4*)&smT[(16 + lo) * 68 + r0] = a1;
      } else {
        *(f32x4*)&restT[lo * 68 + r0] = a0;
        *(f32x4*)&restT[(16 + lo) * 68 + r0] = a1;
      }
      __syncthreads();
      // gating: thread -> (row r, elem E0+j)
      {
        const int r = tid >> 3, j = tid & 7;
        const int n = (wg & 127) >> 3;
        float m1 = -1e30f, m2 = -1e30f;
        float l1[16], l2[16];
        #pragma unroll
        for (int i = 0; i < 16; ++i){
          l1[i] = smT[i * 68 + r]; l2[i] = smT[(16 + i) * 68 + r];
          m1 = fmaxf(m1, l1[i]);   m2 = fmaxf(m2, l2[i]);
        }
        float s1 = 0.f, s2 = 0.f, cu1 = 0.f, cu2 = 0.f;
        #pragma unroll
        for (int i = 0; i < 16; ++i){
          float e1 = __expf(l1[i] - m1), e2 = __expf(l2[i] - m2);
          s1 += e1; s2 += e2;
          if (i <= n){ cu1 += e1; cu2 += e2; }
        }
        const float cin = 1.f - cu1 / s1;
        const float cf  = cu2 / s2;
        const float ov  = cf * cin;
        const float og = restT[j * 68 + r];
        const float ce = restT[(8 + j) * 68 + r];
        const float ig = restT[(16 + j) * 68 + r];
        const float fg = restT[(24 + j) * 68 + r];
        const float ogv = 1.f / (1.f + __expf(-og));
        const float inv = 1.f / (1.f + __expf(-ig));
        const float fgv = 1.f / (1.f + __expf(-fg));
        const float cev = tanhf(ce);
        if (t == 0) creg = 0.f;
        const float fga = fgv * ov + (cf - ov);
        const float iga = inv * ov + (cin - ov);
        const float cy  = fga * creg + iga * cev;
        creg = cy;
        const float hy = ogv * tanhf(cy);
        const u16 hb = f2bf(hy);
        if (lay == 0){
          *(volatile u16*)&hA[(size_t)t * BH + r * HID + E0 + j] = hb;
        } else {
          out[((size_t)t * BATCH + r) * HID + E0 + j] = hy;
          *(volatile u16*)&hB[(size_t)t * BH + r * HID + E0 + j] = hb;
        }
      }
    }
    // ---- arrival: drain data, then slot store (no RMW) ----
    asm volatile("s_waitcnt vmcnt(0)" ::: "memory");
    __syncthreads();
    if (tid == 0) *(volatile unsigned*)&slots[wg * 32] = (unsigned)(s + 1);
    // ---- slack: next epoch's ih-product from LDS/L2 weights ----
    if (lay == 0){
      if (s <= T_LEN - 2) slack_mm(x + (size_t)(s + 1) * BH);
    } else {
      if (s >= 1 && s <= T_LEN) slack_mm(hA + (size_t)(s - 1) * BH);
    }
    // ---- barrier: master scans slots, sets flag; others poll flag ----
    const unsigned tg = (unsigned)(s + 1);
    if (wg == 0){
      if (wave == 0){
        for (;;){
          int ok = 1;
          #pragma unroll
          for (int q = 0; q < 4; ++q)
            ok &= (*(volatile const unsigned*)&slots[(lane + q * 64) * 32] >= tg);
          if (__all(ok)) break;
          __builtin_amdgcn_s_sleep(2);
        }
        if (lane == 0) *(volatile unsigned*)flag = tg;
      }
    } else {
      if (tid == 0)
        while (*(volatile const unsigned*)flag < tg) __builtin_amdgcn_s_sleep(4);
    }
    __syncthreads();
  }
}

// ---- launch -----------------------------------------------------------------

extern "C" void kernel_launch(void* const* d_in, const int* in_sizes, int n_in,
                              void* d_out, int out_size, void* d_ws, size_t ws_size,
                              hipStream_t stream)
{
  (void)in_sizes; (void)n_in; (void)out_size; (void)ws_size;
  const int*   tokens = (const int*)d_in[0];
  const float* emb    = (const float*)d_in[1];
  const float* Wih0   = (const float*)d_in[2];
  const float* bih0   = (const float*)d_in[3];
  const float* Whh0   = (const float*)d_in[4];
  const float* bhh0   = (const float*)d_in[5];
  const float* Wih1   = (const float*)d_in[6];
  const float* bih1   = (const float*)d_in[7];
  const float* Whh1   = (const float*)d_in[8];
  const float* bhh1   = (const float*)d_in[9];
  float* out = (float*)d_out;

  char* ws = (char*)d_ws;
  u16*   Wt0    = (u16*)(ws);                     // 16,908,288
  u16*   Wt1    = (u16*)(ws + 16908288);          // 16,908,288
  u16*   x      = (u16*)(ws + 33816576);          // 33,554,432
  u16*   hA     = (u16*)(ws + 67371008);          // 33,554,432 (h1 full history)
  u16*   hB     = (u16*)(ws + 100925440);         // 33,554,432 (h2 full history)
  float* bias0  = (float*)(ws + 134479872);       // 16,512
  float* bias1  = (float*)(ws + 134496384);       // 16,512
  unsigned* slots = (unsigned*)(ws + 134512896);  // 32,768 (256 x 128B)
  unsigned* flag  = (unsigned*)(ws + 134545664);  // 128
  // total 134,545,792 bytes

  repackW<<<dim3(64,129), dim3(32,32), 0, stream>>>(Wih0, Whh0, Wt0);
  repackW<<<dim3(64,129), dim3(32,32), 0, stream>>>(Wih1, Whh1, Wt1);
  gatherX<<<16384, 256, 0, stream>>>(tokens, emb, x, out + 16777216);
  biasK<<<17, 256, 0, stream>>>(bih0, bhh0, bih1, bhh1, bias0, bias1);
  hipMemsetAsync(slots, 0, 33024, stream);

  persist<<<NWG, 512, 0, stream>>>(Wt0, Wt1, bias0, bias1, x, hA, hB,
                                   out, slots, flag);
}